// Round 18
// baseline (627.396 us; speedup 1.0000x reference)
//
// AdiabaticTDDFTNN v18 — v17 + L2 single 9-row window (removes the 12
// redundant ds_read_b128/thread of the old two-pass L2). All else = v17
// (passed, 498us, absmax 3.9e-3).

#include <hip/hip_runtime.h>

namespace v18 {
constexpr int B = 128, L = 128, T = 127;
constexpr int NT = 512;
constexpr int RS = 52;                 // row stride: delta ≡ 20 mod 32
struct SM {
  float A0[13 * RS];                   // sites -6..6   (row = o+6); var rows 4..8
  float A1[17 * RS];                   // sites -8..8
  float A2[21 * RS];                   // sites -10..10
  float W3T[5 * RS];                   // [k][ci48]
  float W0L[200];                      // W0 raw
  float PRE0[40];                      // b0 + sum_k w0
  float V[2][20];                      // v at o=-8..8, double-buffered by t&1
  float VC;
};
constexpr int SMF = sizeof(SM) / 4;
}

#define CONV_SITE(RARR, I, WREG, BIAS, DSTPTR)                                  \
  {                                                                             \
    float4 ac0 = make_float4(0,0,0,0), ac1 = ac0, ac2 = ac0;                    \
    _Pragma("unroll")                                                           \
    for (int k = 0; k < 5; ++k) {                                               \
      const float4 a0v = RARR[(I) + k][0], a1v = RARR[(I) + k][1],              \
                   a2v = RARR[(I) + k][2];                                      \
      const float4 wa = WREG[k*3], wb = WREG[k*3+1], wc = WREG[k*3+2];          \
      ac0.x = fmaf(wa.x, a0v.x, ac0.x); ac0.y = fmaf(wa.y, a0v.y, ac0.y);       \
      ac0.z = fmaf(wa.z, a0v.z, ac0.z); ac0.w = fmaf(wa.w, a0v.w, ac0.w);       \
      ac1.x = fmaf(wb.x, a1v.x, ac1.x); ac1.y = fmaf(wb.y, a1v.y, ac1.y);       \
      ac1.z = fmaf(wb.z, a1v.z, ac1.z); ac1.w = fmaf(wb.w, a1v.w, ac1.w);       \
      ac2.x = fmaf(wc.x, a2v.x, ac2.x); ac2.y = fmaf(wc.y, a2v.y, ac2.y);       \
      ac2.z = fmaf(wc.z, a2v.z, ac2.z); ac2.w = fmaf(wc.w, a2v.w, ac2.w);       \
    }                                                                           \
    float red = (ac0.x+ac0.y+ac0.z+ac0.w) + (ac1.x+ac1.y+ac1.z+ac1.w)          \
              + (ac2.x+ac2.y+ac2.z+ac2.w);                                      \
    red += __shfl_xor(red, 1); red += __shfl_xor(red, 2);                       \
    if (cg == 0) *(DSTPTR) = fmaxf(red + (BIAS), 0.0f);                         \
  }

__global__ __launch_bounds__(512, 2)
void adia_v18(const float* __restrict__ hg0,
              const float* __restrict__ W0g, const float* __restrict__ B0g,
              const float* __restrict__ W1g, const float* __restrict__ B1g,
              const float* __restrict__ W2g, const float* __restrict__ B2g,
              const float* __restrict__ W3g, const float* __restrict__ B3g,
              float* __restrict__ zml, float* __restrict__ psf,
              int psiInterleaved, float dt)
{
  using namespace v18;
  __shared__ SM sm;
  const int tid  = threadIdx.x;
  const int bi   = blockIdx.x;
  const int lane = tid & 63;
  const float dtH = 0.5f * dt;
  const float dtS = dt * (1.0f / 6.0f);
  const float* __restrict__ hg = hg0 + (size_t)bi * (128 * L);

  const bool convT = (tid < 480);
  const int  co = tid / 12;
  const int  rr = tid - co * 12;
  const int  sh = rr >> 2;
  const int  cg = rr & 3;
  const bool l3T = (tid >= 444);
  const int  i3  = tid - 444;
  const int  s3  = i3 >> 2;
  const int  cg3 = i3 & 3;

  // ---- one-time: W1/W2 slices into registers ----
  float4 w1r[15], w2r[15];
  float  b1r = 0.f, b2r = 0.f;
  if (convT) {
    b1r = B1g[co]; b2r = B2g[co];
    #pragma unroll
    for (int k = 0; k < 5; ++k)
      #pragma unroll
      for (int q = 0; q < 3; ++q) {
        float4 a, b;
        #pragma unroll
        for (int e = 0; e < 4; ++e) {
          const int ci = cg * 12 + q * 4 + e;
          float va = 0.f, vb = 0.f;
          if (ci < 40) {
            va = W1g[(co * 40 + ci) * 5 + k];
            vb = W2g[(co * 40 + ci) * 5 + k];
          }
          (&a.x)[e] = va; (&b.x)[e] = vb;
        }
        w1r[k * 3 + q] = a; w2r[k * 3 + q] = b;
      }
  }
  const float b3r = l3T ? B3g[0] : 0.f;

  // ---- zero LDS + constant output regions ----
  for (int e = tid; e < SMF; e += NT) ((float*)&sm)[e] = 0.f;
  if (tid < 128) zml[(size_t)bi * (128 * L) + 127 * L + tid] = 0.0f;
  if (psiInterleaved) {
    float4* zp = reinterpret_cast<float4*>(psf + (size_t)bi * (2 * L * L) + 2 * L);
    const float4 nil = make_float4(0.f, 0.f, 0.f, 0.f);
    for (int j = tid; j < 16256; j += NT) zp[j] = nil;
  } else {
    float4* zp = reinterpret_cast<float4*>(psf + (size_t)bi * (L * L) + L);
    const float4 nil = make_float4(0.f, 0.f, 0.f, 0.f);
    for (int j = tid; j < 4064; j += NT) zp[j] = nil;
  }
  __syncthreads();

  // ---- tables: PRE0 + A0 halos; W0L; W3T ----
  if (tid < 40) {
    float s = B0g[tid];
    #pragma unroll
    for (int k = 0; k < 5; ++k) s += W0g[tid * 5 + k];
    sm.PRE0[tid] = s;
    const float a0c = fmaxf(s, 0.0f);
    #pragma unroll
    for (int r = 0; r < 4; ++r) {
      sm.A0[r * RS + tid]       = a0c;
      sm.A0[(9 + r) * RS + tid] = a0c;
    }
  }
  for (int e = tid; e < 200; e += NT) sm.W0L[e] = W0g[e];
  for (int e = tid; e < 5 * RS; e += NT) {
    const int k = e / RS, c = e - k * RS;
    sm.W3T[e] = (c < 40) ? W3g[c * 5 + k] : 0.f;
  }
  __syncthreads();

  // ---- a1c (conv of constant column) -> A1 halos ----
  if (convT) {
    const float4* ar = (const float4*)&sm.A0[cg * 12];
    const float4 v0 = ar[0], v1 = ar[1], v2 = ar[2];
    float4 ac0 = make_float4(0,0,0,0), ac1 = ac0, ac2 = ac0;
    #pragma unroll
    for (int k = 0; k < 5; ++k) {
      const float4 wa = w1r[k*3], wb = w1r[k*3+1], wc = w1r[k*3+2];
      ac0.x = fmaf(wa.x, v0.x, ac0.x); ac0.y = fmaf(wa.y, v0.y, ac0.y);
      ac0.z = fmaf(wa.z, v0.z, ac0.z); ac0.w = fmaf(wa.w, v0.w, ac0.w);
      ac1.x = fmaf(wb.x, v1.x, ac1.x); ac1.y = fmaf(wb.y, v1.y, ac1.y);
      ac1.z = fmaf(wb.z, v1.z, ac1.z); ac1.w = fmaf(wb.w, v1.w, ac1.w);
      ac2.x = fmaf(wc.x, v2.x, ac2.x); ac2.y = fmaf(wc.y, v2.y, ac2.y);
      ac2.z = fmaf(wc.z, v2.z, ac2.z); ac2.w = fmaf(wc.w, v2.w, ac2.w);
    }
    float red = (ac0.x+ac0.y+ac0.z+ac0.w)+(ac1.x+ac1.y+ac1.z+ac1.w)+(ac2.x+ac2.y+ac2.z+ac2.w);
    red += __shfl_xor(red, 1); red += __shfl_xor(red, 2);
    if (cg == 0 && sh == 0) {
      const float a1c = fmaxf(red + b1r, 0.0f);
      #pragma unroll
      for (int r = 0; r < 4; ++r) {
        sm.A1[r * RS + co]        = a1c;
        sm.A1[(13 + r) * RS + co] = a1c;
      }
    }
  }
  __syncthreads();

  // ---- a2c -> A2 halos ----
  if (convT) {
    const float4* ar = (const float4*)&sm.A1[cg * 12];
    const float4 v0 = ar[0], v1 = ar[1], v2 = ar[2];
    float4 ac0 = make_float4(0,0,0,0), ac1 = ac0, ac2 = ac0;
    #pragma unroll
    for (int k = 0; k < 5; ++k) {
      const float4 wa = w2r[k*3], wb = w2r[k*3+1], wc = w2r[k*3+2];
      ac0.x = fmaf(wa.x, v0.x, ac0.x); ac0.y = fmaf(wa.y, v0.y, ac0.y);
      ac0.z = fmaf(wa.z, v0.z, ac0.z); ac0.w = fmaf(wa.w, v0.w, ac0.w);
      ac1.x = fmaf(wb.x, v1.x, ac1.x); ac1.y = fmaf(wb.y, v1.y, ac1.y);
      ac1.z = fmaf(wb.z, v1.z, ac1.z); ac1.w = fmaf(wb.w, v1.w, ac1.w);
      ac2.x = fmaf(wc.x, v2.x, ac2.x); ac2.y = fmaf(wc.y, v2.y, ac2.y);
      ac2.z = fmaf(wc.z, v2.z, ac2.z); ac2.w = fmaf(wc.w, v2.w, ac2.w);
    }
    float red = (ac0.x+ac0.y+ac0.z+ac0.w)+(ac1.x+ac1.y+ac1.z+ac1.w)+(ac2.x+ac2.y+ac2.z+ac2.w);
    red += __shfl_xor(red, 1); red += __shfl_xor(red, 2);
    if (cg == 0 && sh == 0) {
      const float a2c = fmaxf(red + b2r, 0.0f);
      #pragma unroll
      for (int r = 0; r < 4; ++r) {
        sm.A2[r * RS + co]        = a2c;
        sm.A2[(17 + r) * RS + co] = a2c;
      }
    }
  }
  __syncthreads();

  // ---- vc ----
  if (l3T && s3 == 0) {
    float acc = 0.f;
    #pragma unroll
    for (int k = 0; k < 5; ++k) {
      const float4* wr = (const float4*)&sm.W3T[k * RS + cg3 * 12];
      const float4* ar = (const float4*)&sm.A2[cg3 * 12];
      #pragma unroll
      for (int q = 0; q < 3; ++q) {
        const float4 w = wr[q], a = ar[q];
        acc = fmaf(w.x, a.x, fmaf(w.y, a.y, fmaf(w.z, a.z, fmaf(w.w, a.w, acc))));
      }
    }
    acc += __shfl_xor(acc, 1); acc += __shfl_xor(acc, 2);
    if (cg3 == 0) sm.VC = acc + b3r;
  }
  __syncthreads();

  // ---- wave0 persistent state + prologue L0(t=0) ----
  const float c0 = 0.70710678118654752440f;
  float uR0 = c0, uI0 = 0.f, uR1 = c0, uI1 = 0.f;
  float hA0 = 0.f, hA1 = 0.f, hB0 = 0.f, hB1 = 0.f, hP0 = 0.f, hP1 = 0.f;
  float mS0 = 0.f, mS1 = 0.f;                     // deferred mag store regs
  const int s0 = 2 * lane, s1 = s0 + 1;
  if (tid < 64) {
    const float2 h0 = *(const float2*)&hg[0 * L + s0];
    const float2 h1 = *(const float2*)&hg[1 * L + s0];
    const float2 h2 = *(const float2*)&hg[2 * L + s0];
    hA0 = h0.x; hA1 = h0.y; hB0 = h1.x; hB1 = h1.y; hP0 = h2.x; hP1 = h2.y;
    const float z00 = 1.0f - 2.0f * (uR0 * uR0 + uI0 * uI0);
    const float dl  = z00 - 1.0f;
    #pragma unroll
    for (int q = 0; q < 4; ++q) {
      const int m = lane + (q << 6);
      if (m < 200) {
        const int c5 = m / 5, jj = m - c5 * 5;
        sm.A0[(jj + 4) * RS + c5] =
            fmaxf(fmaf(sm.W0L[c5 * 5 + (4 - jj)], dl, sm.PRE0[c5]), 0.0f);
      }
    }
  }
  __syncthreads();

  // ring RK4: full 128-site step; mags -> mS regs (store deferred).
  auto ring = [&](const float* __restrict__ Vb) {
    float v0 = sm.VC, v1 = sm.VC;
    if (s0 <= 8) v0 = Vb[s0 + 8]; else if (s0 >= 120) v0 = Vb[s0 - 120];
    if (s1 <= 8) v1 = Vb[s1 + 8]; else if (s1 >= 120) v1 = Vb[s1 - 120];
    const float f10 = v0 + hA0, f11 = v1 + hA1;
    const float f40 = v0 + hB0, f41 = v1 + hB1;

    float y0R = uR0, y0I = uI0, y1R = uR1, y1I = uI1;
    float aR0 = 0.f, aI0 = 0.f, aR1 = 0.f, aI1 = 0.f;
    #pragma unroll
    for (int st = 0; st < 4; ++st) {
      const bool fin = (st == 3);
      const float f0 = fin ? f40 : f10;
      const float f1 = fin ? f41 : f11;
      const float ymR = __shfl(y1R, (lane + 63) & 63);
      const float ymI = __shfl(y1I, (lane + 63) & 63);
      const float ypR = __shfl(y0R, (lane + 1) & 63);
      const float ypI = __shfl(y0I, (lane + 1) & 63);
      const float d0 = 2.0f + f0, d1 = 2.0f + f1;
      const float hRa = fmaf(d0, y0R, -ymR) - y1R;
      const float hIa = fmaf(d0, y0I, -ymI) - y1I;
      const float hRb = fmaf(d1, y1R, -y0R) - ypR;
      const float hIb = fmaf(d1, y1I, -y0I) - ypI;
      const float kR0 = hIa, kI0 = -hRa, kR1 = hIb, kI1 = -hRb;
      if (st == 0) { aR0 = dt * kR0; aI0 = dt * kI0; aR1 = dt * kR1; aI1 = dt * kI1; }
      else {
        const float w = fin ? 1.0f : 2.0f;
        aR0 = fmaf(w, kR0, aR0); aI0 = fmaf(w, kI0, aI0);
        aR1 = fmaf(w, kR1, aR1); aI1 = fmaf(w, kI1, aI1);
      }
      if (fin) {
        uR0 = fmaf(dtS, aR0, uR0); uI0 = fmaf(dtS, aI0, uI0);
        uR1 = fmaf(dtS, aR1, uR1); uI1 = fmaf(dtS, aI1, uI1);
      } else {
        const float stp = (st == 2) ? dt : dtH;
        y0R = fmaf(stp, kR0, uR0); y0I = fmaf(stp, kI0, uI0);
        y1R = fmaf(stp, kR1, uR1); y1I = fmaf(stp, kI1, uI1);
      }
    }
    mS0 = 1.0f - 2.0f * (uR0 * uR0 + uI0 * uI0);
    mS1 = 1.0f - 2.0f * (uR1 * uR1 + uI1 * uI1);
  };

  // ================= time loop: 4 phases =================
  for (int t = 0; t < T; ++t) {
    // ---- P1: L1(t) ----
    if (convT) {
      const int baseo = -4 + sh * 3;
      float4 R[7][3];
      #pragma unroll
      for (int r = 0; r < 7; ++r) {
        const float4* ar = (const float4*)&sm.A0[(baseo + 4 + r) * RS + cg * 12];
        R[r][0] = ar[0]; R[r][1] = ar[1]; R[r][2] = ar[2];
      }
      #pragma unroll
      for (int i = 0; i < 3; ++i)
        CONV_SITE(R, i, w1r, b1r, &sm.A1[(baseo + i + 8) * RS + co]);
    }
    __syncthreads();

    // ---- P2: L2(t) — single 9-row window (5 sites, rows b+6 .. b+14) ----
    if (convT) {
      const int b = (sh == 0) ? -6 : ((sh == 1) ? -2 : 2);
      float4 R[9][3];
      #pragma unroll
      for (int r = 0; r < 9; ++r) {
        const float4* ar = (const float4*)&sm.A1[(b + 6 + r) * RS + cg * 12];
        R[r][0] = ar[0]; R[r][1] = ar[1]; R[r][2] = ar[2];
      }
      #pragma unroll
      for (int i = 0; i < 5; ++i)
        CONV_SITE(R, i, w2r, b2r, &sm.A2[(b + i + 10) * RS + co]);
    }
    __syncthreads();

    // ---- P3: L3(t) -> V[t&1]  ∥  wave0: ring(t-1) + h shift ----
    if (l3T) {
      float4 AR[5][3];
      #pragma unroll
      for (int k = 0; k < 5; ++k) {
        const float4* ar = (const float4*)&sm.A2[(s3 + k) * RS + cg3 * 12];
        AR[k][0] = ar[0]; AR[k][1] = ar[1]; AR[k][2] = ar[2];
      }
      float4 ac = make_float4(0,0,0,0), ac2 = ac, ac3 = ac;
      #pragma unroll
      for (int k = 0; k < 5; ++k) {
        const float4* wr = (const float4*)&sm.W3T[k * RS + cg3 * 12];
        const float4 w0 = wr[0], w1 = wr[1], w2 = wr[2];
        ac.x  = fmaf(w0.x, AR[k][0].x, ac.x);  ac.y  = fmaf(w0.y, AR[k][0].y, ac.y);
        ac.z  = fmaf(w0.z, AR[k][0].z, ac.z);  ac.w  = fmaf(w0.w, AR[k][0].w, ac.w);
        ac2.x = fmaf(w1.x, AR[k][1].x, ac2.x); ac2.y = fmaf(w1.y, AR[k][1].y, ac2.y);
        ac2.z = fmaf(w1.z, AR[k][1].z, ac2.z); ac2.w = fmaf(w1.w, AR[k][1].w, ac2.w);
        ac3.x = fmaf(w2.x, AR[k][2].x, ac3.x); ac3.y = fmaf(w2.y, AR[k][2].y, ac3.y);
        ac3.z = fmaf(w2.z, AR[k][2].z, ac3.z); ac3.w = fmaf(w2.w, AR[k][2].w, ac3.w);
      }
      float acc = (ac.x+ac.y+ac.z+ac.w) + (ac2.x+ac2.y+ac2.z+ac2.w)
                + (ac3.x+ac3.y+ac3.z+ac3.w);
      acc += __shfl_xor(acc, 1); acc += __shfl_xor(acc, 2);
      if (cg3 == 0) sm.V[t & 1][s3] = acc + b3r;
    } else if (tid < 64) {
      if (t > 0) {
        ring(sm.V[(t + 1) & 1]);               // u(t); mags -> mS regs
        hA0 = hB0; hA1 = hB1; hB0 = hP0; hB1 = hP1;
      }
    }
    __syncthreads();

    // ---- P4: wave0: deferred stores/prefetch, cone -> z0, L0 ----
    if (tid < 64) {
      if (t > 0)
        *(float2*)&zml[(size_t)bi * (128 * L) + (size_t)(127 - t) * L + s0] =
            make_float2(mS0, mS1);
      if (t > 0 && t + 2 < 128) {
        const float2 hp = *(const float2*)&hg[(t + 2) * L + s0];
        hP0 = hp.x; hP1 = hp.y;
      }
      const float* __restrict__ Vb = sm.V[t & 1];
      const int s  = (lane + 124) & 127;        // site lane-4 mod 128
      const int hl = s >> 1, pe = s & 1;
      float ea = __shfl(hA0, hl), eb = __shfl(hA1, hl);
      const float hAs = pe ? eb : ea;
      ea = __shfl(hB0, hl); eb = __shfl(hB1, hl);
      const float hBs = pe ? eb : ea;
      ea = __shfl(uR0, hl); eb = __shfl(uR1, hl);
      const float usR = pe ? eb : ea;
      ea = __shfl(uI0, hl); eb = __shfl(uI1, hl);
      const float usI = pe ? eb : ea;
      const float vs = (s <= 8) ? Vb[s + 8] : ((s >= 120) ? Vb[s - 120] : sm.VC);
      const float f1 = vs + hAs, f4 = vs + hBs;
      float yR = usR, yI = usI, aR = 0.f, aI = 0.f, zc = 0.f;
      #pragma unroll
      for (int st = 0; st < 4; ++st) {
        const bool fin = (st == 3);
        const float ff = fin ? f4 : f1;
        const float ymR = __shfl(yR, (lane + 63) & 63);
        const float ymI = __shfl(yI, (lane + 63) & 63);
        const float ypR = __shfl(yR, (lane + 1) & 63);
        const float ypI = __shfl(yI, (lane + 1) & 63);
        const float d  = 2.0f + ff;
        const float hRr = fmaf(d, yR, -ymR) - ypR;
        const float hIr = fmaf(d, yI, -ymI) - ypI;
        const float kR = hIr, kI = -hRr;
        if (st == 0) { aR = dt * kR; aI = dt * kI; }
        else { const float w = fin ? 1.0f : 2.0f; aR = fmaf(w, kR, aR); aI = fmaf(w, kI, aI); }
        if (fin) {
          const float ufR = fmaf(dtS, aR, usR), ufI = fmaf(dtS, aI, usI);
          zc = 1.0f - 2.0f * (ufR * ufR + ufI * ufI);
        } else {
          const float stp = (st == 2) ? dt : dtH;
          yR = fmaf(stp, kR, usR); yI = fmaf(stp, kI, usI);
        }
      }
      const float z0b = __shfl(zc, 4);          // lane 4 holds site 0 (exact)
      const float dl  = z0b - 1.0f;
      #pragma unroll
      for (int q = 0; q < 4; ++q) {
        const int m = lane + (q << 6);
        if (m < 200) {
          const int c5 = m / 5, jj = m - c5 * 5;
          sm.A0[(jj + 4) * RS + c5] =
              fmaxf(fmaf(sm.W0L[c5 * 5 + (4 - jj)], dl, sm.PRE0[c5]), 0.0f);
        }
      }
    }
    __syncthreads();
  }

  // ---- epilogue: pending ring(126) -> u(127), mag row 0, psi ----
  if (tid < 64) {
    ring(sm.V[(T + 1) & 1]);                    // V(126) at parity 0
    *(float2*)&zml[(size_t)bi * (128 * L) + s0] = make_float2(mS0, mS1);
    if (psiInterleaved) {
      *(float4*)&psf[(size_t)bi * (2 * L * L) + 4 * lane] =
          make_float4(uR0, uI0, uR1, uI1);
    } else {
      *(float2*)&psf[(size_t)bi * (L * L) + s0] = make_float2(uR0, uR1);
    }
  }
}

extern "C" void kernel_launch(void* const* d_in, const int* in_sizes, int n_in,
                              void* d_out, int out_size, void* d_ws, size_t ws_size,
                              hipStream_t stream) {
  (void)d_ws; (void)ws_size;
  using namespace v18;

  const float* in[9] = {nullptr};
  int seen200 = 0, seen40 = 0, seen8000 = 0;
  for (int i = 0; i < n_in && i < 16; ++i) {
    const int sz = in_sizes[i];
    const float* q = (const float*)d_in[i];
    if      (sz == 2097152) in[0] = q;
    else if (sz == 8000)    { in[seen8000 ? 5 : 3] = q; ++seen8000; }
    else if (sz == 200)     { in[seen200  ? 7 : 1] = q; ++seen200;  }
    else if (sz == 40)      { in[seen40 == 0 ? 2 : (seen40 == 1 ? 4 : 6)] = q; ++seen40; }
    else if (sz == 1)       in[8] = q;
  }
  bool ok = true;
  for (int i = 0; i < 9; ++i) ok = ok && (in[i] != nullptr);
  if (!ok) for (int i = 0; i < 9; ++i) in[i] = (const float*)d_in[i];

  const size_t zCount = (size_t)B * 128 * L;
  const long long psiFloats = (long long)out_size - (long long)zCount;
  const int psiInterleaved = (psiFloats >= (long long)2 * L * L * B) ? 1 : 0;

  float* zml = (float*)d_out;
  float* psf = zml + zCount;
  const float dt = (float)(6.4 / 127.0);

  hipLaunchKernelGGL(adia_v18, dim3(B), dim3(NT), 0, stream,
                     in[0], in[1], in[2], in[3], in[4], in[5], in[6], in[7], in[8],
                     zml, psf, psiInterleaved, dt);
}

// Round 19
// 116.813 us; speedup vs baseline: 5.3709x; 5.3709x over previous
//
// AdiabaticTDDFTNN v19 — tabulated v(z0): the conv stack is a function of ONE
// scalar (z[l!=0]==1 exactly), so kernel A precomputes v at 17 sites on a
// 2048-point z0 grid (v17's proven conv code verbatim); kernel B runs the 127
// RK4 steps on a single wave with LDS table interpolation — no barriers.

#include <hip/hip_runtime.h>

namespace v19 {
constexpr int B = 128, L = 128, T = 127;
constexpr int RS = 52;
constexpr int NPT = 2048, ROW = 19;
constexpr int VCOFF = NPT * ROW;                 // 38912 floats
constexpr float ZMIN = -31.0f;
#define DZV   (32.0f / 2047.0f)
#define INVDZ (2047.0f / 32.0f)
struct SMA {
  float A0[13 * RS];
  float A1[17 * RS];
  float A2[21 * RS];
  float W3T[5 * RS];
  float PRE0[40];
};
constexpr int SMAF = sizeof(SMA) / 4;
}

#define CONV_SITE(RARR, I, WREG, BIAS, DSTPTR)                                  \
  {                                                                             \
    float4 ac0 = make_float4(0,0,0,0), ac1 = ac0, ac2 = ac0;                    \
    _Pragma("unroll")                                                           \
    for (int k = 0; k < 5; ++k) {                                               \
      const float4 a0v = RARR[(I) + k][0], a1v = RARR[(I) + k][1],              \
                   a2v = RARR[(I) + k][2];                                      \
      const float4 wa = WREG[k*3], wb = WREG[k*3+1], wc = WREG[k*3+2];          \
      ac0.x = fmaf(wa.x, a0v.x, ac0.x); ac0.y = fmaf(wa.y, a0v.y, ac0.y);       \
      ac0.z = fmaf(wa.z, a0v.z, ac0.z); ac0.w = fmaf(wa.w, a0v.w, ac0.w);       \
      ac1.x = fmaf(wb.x, a1v.x, ac1.x); ac1.y = fmaf(wb.y, a1v.y, ac1.y);       \
      ac1.z = fmaf(wb.z, a1v.z, ac1.z); ac1.w = fmaf(wb.w, a1v.w, ac1.w);       \
      ac2.x = fmaf(wc.x, a2v.x, ac2.x); ac2.y = fmaf(wc.y, a2v.y, ac2.y);       \
      ac2.z = fmaf(wc.z, a2v.z, ac2.z); ac2.w = fmaf(wc.w, a2v.w, ac2.w);       \
    }                                                                           \
    float red = (ac0.x+ac0.y+ac0.z+ac0.w) + (ac1.x+ac1.y+ac1.z+ac1.w)          \
              + (ac2.x+ac2.y+ac2.z+ac2.w);                                      \
    red += __shfl_xor(red, 1); red += __shfl_xor(red, 2);                       \
    if (cg == 0) *(DSTPTR) = fmaxf(red + (BIAS), 0.0f);                         \
  }

// ---------- Kernel A: build the v(z0) table (v17 conv code, 8 pts/block) ----
__global__ __launch_bounds__(512, 2)
void adia_v19_table(const float* __restrict__ W0g, const float* __restrict__ B0g,
                    const float* __restrict__ W1g, const float* __restrict__ B1g,
                    const float* __restrict__ W2g, const float* __restrict__ B2g,
                    const float* __restrict__ W3g, const float* __restrict__ B3g,
                    float* __restrict__ Tg)
{
  using namespace v19;
  __shared__ SMA sm;
  const int tid = threadIdx.x;
  const bool convT = (tid < 480);
  const int  co = tid / 12;
  const int  rr = tid - co * 12;
  const int  sh = rr >> 2;
  const int  cg = rr & 3;
  const int  co0 = tid / 5;
  const int  j0  = tid - co0 * 5;
  const bool l3T = (tid >= 444);
  const int  i3  = tid - 444;
  const int  s3  = i3 >> 2;
  const int  cg3 = i3 & 3;

  float4 w1r[15], w2r[15];
  float  b1r = 0.f, b2r = 0.f;
  if (convT) {
    b1r = B1g[co]; b2r = B2g[co];
    #pragma unroll
    for (int k = 0; k < 5; ++k)
      #pragma unroll
      for (int q = 0; q < 3; ++q) {
        float4 a, b;
        #pragma unroll
        for (int e = 0; e < 4; ++e) {
          const int ci = cg * 12 + q * 4 + e;
          float va = 0.f, vb = 0.f;
          if (ci < 40) {
            va = W1g[(co * 40 + ci) * 5 + k];
            vb = W2g[(co * 40 + ci) * 5 + k];
          }
          (&a.x)[e] = va; (&b.x)[e] = vb;
        }
        w1r[k * 3 + q] = a; w2r[k * 3 + q] = b;
      }
  }
  const float b3r = l3T ? B3g[0] : 0.f;
  const float w0r = (tid < 200) ? W0g[co0 * 5 + (4 - j0)] : 0.f;

  for (int e = tid; e < SMAF; e += 512) ((float*)&sm)[e] = 0.f;
  __syncthreads();

  if (tid < 40) {
    float s = B0g[tid];
    #pragma unroll
    for (int k = 0; k < 5; ++k) s += W0g[tid * 5 + k];
    sm.PRE0[tid] = s;
    const float a0c = fmaxf(s, 0.0f);
    #pragma unroll
    for (int r = 0; r < 4; ++r) {
      sm.A0[r * RS + tid]       = a0c;
      sm.A0[(9 + r) * RS + tid] = a0c;
    }
  }
  for (int e = tid; e < 5 * RS; e += 512) {
    const int k = e / RS, c = e - k * RS;
    sm.W3T[e] = (c < 40) ? W3g[c * 5 + k] : 0.f;
  }
  __syncthreads();
  const float pre0r = (tid < 200) ? sm.PRE0[co0] : 0.f;

  // a1c -> A1 halos (v17 verbatim)
  if (convT) {
    const float4* ar = (const float4*)&sm.A0[cg * 12];
    const float4 v0 = ar[0], v1 = ar[1], v2 = ar[2];
    float4 ac0 = make_float4(0,0,0,0), ac1 = ac0, ac2 = ac0;
    #pragma unroll
    for (int k = 0; k < 5; ++k) {
      const float4 wa = w1r[k*3], wb = w1r[k*3+1], wc = w1r[k*3+2];
      ac0.x = fmaf(wa.x, v0.x, ac0.x); ac0.y = fmaf(wa.y, v0.y, ac0.y);
      ac0.z = fmaf(wa.z, v0.z, ac0.z); ac0.w = fmaf(wa.w, v0.w, ac0.w);
      ac1.x = fmaf(wb.x, v1.x, ac1.x); ac1.y = fmaf(wb.y, v1.y, ac1.y);
      ac1.z = fmaf(wb.z, v1.z, ac1.z); ac1.w = fmaf(wb.w, v1.w, ac1.w);
      ac2.x = fmaf(wc.x, v2.x, ac2.x); ac2.y = fmaf(wc.y, v2.y, ac2.y);
      ac2.z = fmaf(wc.z, v2.z, ac2.z); ac2.w = fmaf(wc.w, v2.w, ac2.w);
    }
    float red = (ac0.x+ac0.y+ac0.z+ac0.w)+(ac1.x+ac1.y+ac1.z+ac1.w)+(ac2.x+ac2.y+ac2.z+ac2.w);
    red += __shfl_xor(red, 1); red += __shfl_xor(red, 2);
    if (cg == 0 && sh == 0) {
      const float a1c = fmaxf(red + b1r, 0.0f);
      #pragma unroll
      for (int r = 0; r < 4; ++r) {
        sm.A1[r * RS + co]        = a1c;
        sm.A1[(13 + r) * RS + co] = a1c;
      }
    }
  }
  __syncthreads();

  // a2c -> A2 halos (v17 verbatim)
  if (convT) {
    const float4* ar = (const float4*)&sm.A1[cg * 12];
    const float4 v0 = ar[0], v1 = ar[1], v2 = ar[2];
    float4 ac0 = make_float4(0,0,0,0), ac1 = ac0, ac2 = ac0;
    #pragma unroll
    for (int k = 0; k < 5; ++k) {
      const float4 wa = w2r[k*3], wb = w2r[k*3+1], wc = w2r[k*3+2];
      ac0.x = fmaf(wa.x, v0.x, ac0.x); ac0.y = fmaf(wa.y, v0.y, ac0.y);
      ac0.z = fmaf(wa.z, v0.z, ac0.z); ac0.w = fmaf(wa.w, v0.w, ac0.w);
      ac1.x = fmaf(wb.x, v1.x, ac1.x); ac1.y = fmaf(wb.y, v1.y, ac1.y);
      ac1.z = fmaf(wb.z, v1.z, ac1.z); ac1.w = fmaf(wb.w, v1.w, ac1.w);
      ac2.x = fmaf(wc.x, v2.x, ac2.x); ac2.y = fmaf(wc.y, v2.y, ac2.y);
      ac2.z = fmaf(wc.z, v2.z, ac2.z); ac2.w = fmaf(wc.w, v2.w, ac2.w);
    }
    float red = (ac0.x+ac0.y+ac0.z+ac0.w)+(ac1.x+ac1.y+ac1.z+ac1.w)+(ac2.x+ac2.y+ac2.z+ac2.w);
    red += __shfl_xor(red, 1); red += __shfl_xor(red, 2);
    if (cg == 0 && sh == 0) {
      const float a2c = fmaxf(red + b2r, 0.0f);
      #pragma unroll
      for (int r = 0; r < 4; ++r) {
        sm.A2[r * RS + co]        = a2c;
        sm.A2[(17 + r) * RS + co] = a2c;
      }
    }
  }
  __syncthreads();

  // vc (constant column) -> Tg[VCOFF] (block 0 writes)
  if (l3T && s3 == 0) {
    float acc = 0.f;
    #pragma unroll
    for (int k = 0; k < 5; ++k) {
      const float4* wr = (const float4*)&sm.W3T[k * RS + cg3 * 12];
      const float4* ar = (const float4*)&sm.A2[cg3 * 12];
      #pragma unroll
      for (int q = 0; q < 3; ++q) {
        const float4 w = wr[q], a = ar[q];
        acc = fmaf(w.x, a.x, fmaf(w.y, a.y, fmaf(w.z, a.z, fmaf(w.w, a.w, acc))));
      }
    }
    acc += __shfl_xor(acc, 1); acc += __shfl_xor(acc, 2);
    if (cg3 == 0 && blockIdx.x == 0) Tg[VCOFF] = acc + b3r;
  }
  __syncthreads();

  // ---- 8 grid points per block ----
  for (int j = 0; j < 8; ++j) {
    const int p = blockIdx.x * 8 + j;
    const float dl = (ZMIN + (float)p * DZV) - 1.0f;     // delta = z0 - 1

    if (tid < 200)
      sm.A0[(j0 + 4) * RS + co0] = fmaxf(fmaf(w0r, dl, pre0r), 0.0f);
    __syncthreads();

    if (convT) {                                   // L1 (v17 verbatim)
      const int baseo = -4 + sh * 3;
      float4 R[7][3];
      #pragma unroll
      for (int r = 0; r < 7; ++r) {
        const float4* ar = (const float4*)&sm.A0[(baseo + 4 + r) * RS + cg * 12];
        R[r][0] = ar[0]; R[r][1] = ar[1]; R[r][2] = ar[2];
      }
      #pragma unroll
      for (int i = 0; i < 3; ++i)
        CONV_SITE(R, i, w1r, b1r, &sm.A1[(baseo + i + 8) * RS + co]);
    }
    __syncthreads();

    if (convT) {                                   // L2 two-pass (v17 verbatim)
      const int b = (sh == 0) ? -6 : ((sh == 1) ? -2 : 2);
      {
        float4 R[7][3];
        #pragma unroll
        for (int r = 0; r < 7; ++r) {
          const float4* ar = (const float4*)&sm.A1[(b + 6 + r) * RS + cg * 12];
          R[r][0] = ar[0]; R[r][1] = ar[1]; R[r][2] = ar[2];
        }
        #pragma unroll
        for (int i = 0; i < 3; ++i)
          CONV_SITE(R, i, w2r, b2r, &sm.A2[(b + i + 10) * RS + co]);
      }
      {
        float4 R[6][3];
        #pragma unroll
        for (int r = 0; r < 6; ++r) {
          const float4* ar = (const float4*)&sm.A1[(b + 9 + r) * RS + cg * 12];
          R[r][0] = ar[0]; R[r][1] = ar[1]; R[r][2] = ar[2];
        }
        #pragma unroll
        for (int i = 0; i < 2; ++i)
          CONV_SITE(R, i, w2r, b2r, &sm.A2[(b + i + 13) * RS + co]);
      }
    }
    __syncthreads();

    if (l3T) {                                     // L3 -> Tg row p
      float4 AR[5][3];
      #pragma unroll
      for (int k = 0; k < 5; ++k) {
        const float4* ar = (const float4*)&sm.A2[(s3 + k) * RS + cg3 * 12];
        AR[k][0] = ar[0]; AR[k][1] = ar[1]; AR[k][2] = ar[2];
      }
      float4 ac = make_float4(0,0,0,0), ac2 = ac, ac3 = ac;
      #pragma unroll
      for (int k = 0; k < 5; ++k) {
        const float4* wr = (const float4*)&sm.W3T[k * RS + cg3 * 12];
        const float4 w0 = wr[0], w1 = wr[1], w2 = wr[2];
        ac.x  = fmaf(w0.x, AR[k][0].x, ac.x);  ac.y  = fmaf(w0.y, AR[k][0].y, ac.y);
        ac.z  = fmaf(w0.z, AR[k][0].z, ac.z);  ac.w  = fmaf(w0.w, AR[k][0].w, ac.w);
        ac2.x = fmaf(w1.x, AR[k][1].x, ac2.x); ac2.y = fmaf(w1.y, AR[k][1].y, ac2.y);
        ac2.z = fmaf(w1.z, AR[k][1].z, ac2.z); ac2.w = fmaf(w1.w, AR[k][1].w, ac2.w);
        ac3.x = fmaf(w2.x, AR[k][2].x, ac3.x); ac3.y = fmaf(w2.y, AR[k][2].y, ac3.y);
        ac3.z = fmaf(w2.z, AR[k][2].z, ac3.z); ac3.w = fmaf(w2.w, AR[k][2].w, ac3.w);
      }
      float acc = (ac.x+ac.y+ac.z+ac.w) + (ac2.x+ac2.y+ac2.z+ac2.w)
                + (ac3.x+ac3.y+ac3.z+ac3.w);
      acc += __shfl_xor(acc, 1); acc += __shfl_xor(acc, 2);
      if (cg3 == 0) Tg[(size_t)p * ROW + s3] = acc + b3r;
    }
    __syncthreads();
  }
}

// ---------- Kernel B: 127-step RK4 on one wave, table-interp fields ----------
__global__ __launch_bounds__(256)
void adia_v19_main(const float* __restrict__ hg0, const float* __restrict__ Tg,
                   float* __restrict__ zml, float* __restrict__ psf,
                   int psiInterleaved, float dt)
{
  using namespace v19;
  __shared__ float4 TL4[VCOFF / 4];     // 2048*19 floats = 9728 float4
  __shared__ float  vcs;
  const float* TL = (const float*)TL4;
  const int tid  = threadIdx.x;
  const int bi   = blockIdx.x;
  const int lane = tid & 63;
  const float dtH = 0.5f * dt;
  const float dtS = dt * (1.0f / 6.0f);
  const float* __restrict__ hg = hg0 + (size_t)bi * (128 * L);

  // constant output regions
  if (tid < 128) zml[(size_t)bi * (128 * L) + 127 * L + tid] = 0.0f;
  if (psiInterleaved) {
    float4* zp = reinterpret_cast<float4*>(psf + (size_t)bi * (2 * L * L) + 2 * L);
    const float4 nil = make_float4(0.f, 0.f, 0.f, 0.f);
    for (int j = tid; j < 16256; j += 256) zp[j] = nil;
  } else {
    float4* zp = reinterpret_cast<float4*>(psf + (size_t)bi * (L * L) + L);
    const float4 nil = make_float4(0.f, 0.f, 0.f, 0.f);
    for (int j = tid; j < 4064; j += 256) zp[j] = nil;
  }
  // table -> LDS
  for (int e = tid; e < VCOFF / 4; e += 256)
    TL4[e] = reinterpret_cast<const float4*>(Tg)[e];
  if (tid == 0) vcs = Tg[VCOFF];
  __syncthreads();
  if (tid >= 64) return;                 // only wave0 runs the time loop

  const float c0 = 0.70710678118654752440f;
  float uR0 = c0, uI0 = 0.f, uR1 = c0, uI1 = 0.f;
  const int s0 = 2 * lane, s1 = s0 + 1;
  const float2 h0 = *(const float2*)&hg[0 * L + s0];
  const float2 h1 = *(const float2*)&hg[1 * L + s0];
  const float2 h2 = *(const float2*)&hg[2 * L + s0];
  float hA0 = h0.x, hA1 = h0.y, hB0 = h1.x, hB1 = h1.y, hP0 = h2.x, hP1 = h2.y;
  float z0 = 1.0f - 2.0f * (uR0 * uR0 + uI0 * uI0);   // exact t=0 value

  for (int t = 0; t < T; ++t) {
    // ---- v from table (wave-uniform index) ----
    float x = (z0 - ZMIN) * INVDZ;
    x = fminf(fmaxf(x, 0.0f), (float)(NPT - 1) - 0.001f);
    const int i0 = (int)x;
    const float fr = x - (float)i0;
    const int ba = i0 * ROW, bb = ba + ROW;
    float v0 = vcs, v1 = vcs;
    if (s0 <= 8)        { const float a = TL[ba + s0 + 8],  b = TL[bb + s0 + 8];  v0 = fmaf(fr, b - a, a); }
    else if (s0 >= 120) { const float a = TL[ba + s0 - 120], b = TL[bb + s0 - 120]; v0 = fmaf(fr, b - a, a); }
    if (s1 <= 8)        { const float a = TL[ba + s1 + 8],  b = TL[bb + s1 + 8];  v1 = fmaf(fr, b - a, a); }
    else if (s1 >= 120) { const float a = TL[ba + s1 - 120], b = TL[bb + s1 - 120]; v1 = fmaf(fr, b - a, a); }

    const float f10 = v0 + hA0, f11 = v1 + hA1;
    const float f40 = v0 + hB0, f41 = v1 + hB1;

    // ---- ring RK4 (v17 verbatim) ----
    float y0R = uR0, y0I = uI0, y1R = uR1, y1I = uI1;
    float aR0 = 0.f, aI0 = 0.f, aR1 = 0.f, aI1 = 0.f;
    #pragma unroll
    for (int st = 0; st < 4; ++st) {
      const bool fin = (st == 3);
      const float f0 = fin ? f40 : f10;
      const float f1 = fin ? f41 : f11;
      const float ymR = __shfl(y1R, (lane + 63) & 63);
      const float ymI = __shfl(y1I, (lane + 63) & 63);
      const float ypR = __shfl(y0R, (lane + 1) & 63);
      const float ypI = __shfl(y0I, (lane + 1) & 63);
      const float d0 = 2.0f + f0, d1 = 2.0f + f1;
      const float hRa = fmaf(d0, y0R, -ymR) - y1R;
      const float hIa = fmaf(d0, y0I, -ymI) - y1I;
      const float hRb = fmaf(d1, y1R, -y0R) - ypR;
      const float hIb = fmaf(d1, y1I, -y0I) - ypI;
      const float kR0 = hIa, kI0 = -hRa, kR1 = hIb, kI1 = -hRb;
      if (st == 0) { aR0 = dt * kR0; aI0 = dt * kI0; aR1 = dt * kR1; aI1 = dt * kI1; }
      else {
        const float w = fin ? 1.0f : 2.0f;
        aR0 = fmaf(w, kR0, aR0); aI0 = fmaf(w, kI0, aI0);
        aR1 = fmaf(w, kR1, aR1); aI1 = fmaf(w, kI1, aI1);
      }
      if (fin) {
        uR0 = fmaf(dtS, aR0, uR0); uI0 = fmaf(dtS, aI0, uI0);
        uR1 = fmaf(dtS, aR1, uR1); uI1 = fmaf(dtS, aI1, uI1);
      } else {
        const float stp = (st == 2) ? dt : dtH;
        y0R = fmaf(stp, kR0, uR0); y0I = fmaf(stp, kI0, uI0);
        y1R = fmaf(stp, kR1, uR1); y1I = fmaf(stp, kI1, uI1);
      }
    }

    const float m0 = 1.0f - 2.0f * (uR0 * uR0 + uI0 * uI0);
    const float m1 = 1.0f - 2.0f * (uR1 * uR1 + uI1 * uI1);
    *(float2*)&zml[(size_t)bi * (128 * L) + (size_t)(126 - t) * L + s0] =
        make_float2(m0, m1);
    z0 = __shfl(m0, 0);                 // site 0 = lane 0's s0

    hA0 = hB0; hA1 = hB1; hB0 = hP0; hB1 = hP1;
    if (t + 3 < 128) {
      const float2 hp = *(const float2*)&hg[(t + 3) * L + s0];
      hP0 = hp.x; hP1 = hp.y;
    }
  }

  // final psi row 0
  if (psiInterleaved) {
    *(float4*)&psf[(size_t)bi * (2 * L * L) + 4 * lane] =
        make_float4(uR0, uI0, uR1, uI1);
  } else {
    *(float2*)&psf[(size_t)bi * (L * L) + s0] = make_float2(uR0, uR1);
  }
}

extern "C" void kernel_launch(void* const* d_in, const int* in_sizes, int n_in,
                              void* d_out, int out_size, void* d_ws, size_t ws_size,
                              hipStream_t stream) {
  using namespace v19;

  const float* in[9] = {nullptr};
  int seen200 = 0, seen40 = 0, seen8000 = 0;
  for (int i = 0; i < n_in && i < 16; ++i) {
    const int sz = in_sizes[i];
    const float* q = (const float*)d_in[i];
    if      (sz == 2097152) in[0] = q;
    else if (sz == 8000)    { in[seen8000 ? 5 : 3] = q; ++seen8000; }
    else if (sz == 200)     { in[seen200  ? 7 : 1] = q; ++seen200;  }
    else if (sz == 40)      { in[seen40 == 0 ? 2 : (seen40 == 1 ? 4 : 6)] = q; ++seen40; }
    else if (sz == 1)       in[8] = q;
  }
  bool ok = true;
  for (int i = 0; i < 9; ++i) ok = ok && (in[i] != nullptr);
  if (!ok) for (int i = 0; i < 9; ++i) in[i] = (const float*)d_in[i];

  const size_t zCount = (size_t)B * 128 * L;
  const long long psiFloats = (long long)out_size - (long long)zCount;
  const int psiInterleaved = (psiFloats >= (long long)2 * L * L * B) ? 1 : 0;

  float* zml = (float*)d_out;
  float* psf = zml + zCount;
  float* Tg  = (float*)d_ws;            // needs (VCOFF+1)*4 = 155,652 B
  const float dt = (float)(6.4 / 127.0);

  hipLaunchKernelGGL(adia_v19_table, dim3(NPT / 8), dim3(512), 0, stream,
                     in[1], in[2], in[3], in[4], in[5], in[6], in[7], in[8], Tg);
  hipLaunchKernelGGL(adia_v19_main, dim3(B), dim3(256), 0, stream,
                     in[0], Tg, zml, psf, psiInterleaved, dt);
  (void)ws_size;
}